// Round 20
// baseline (89.248 us; speedup 1.0000x reference)
//
#include <hip/hip_runtime.h>

#define T_STEPS 50000
#define HID     512
#define LBASE   200
#define CHUNKS  250            // 50000 = 250*200 exactly -> NO tail chunk
#define WARMCH  2
#define WARM    (WARMCH * LBASE)   // 400-step warmup (validated r5/r6)
#define SDMAX   (WARM + LBASE)     // 600 float4 = 9600 B LDS

static_assert(T_STEPS == CHUNKS * LBASE, "exact chunking");
static_assert(LBASE % 8 == 0 && WARM % 8 == 0, "8-step bodies");

#define PIN2D(a) asm volatile("" : "+v"(a.x), "+v"(a.y))

// pet from raw x row (x is 600 KB -> L2-resident after first touch)
#define PET_FROM_X(t, P, TT, PE)                                              \
    const float P  = x[3 * (t) + 0];                                          \
    const float TT = x[3 * (t) + 1];                                          \
    const float ld_##P = x[3 * (t) + 2];                                      \
    const float esat_##P = 0.611f * __expf(17.3f * TT / (TT + 237.3f));       \
    const float PE = 29.8f * (ld_##P * 24.0f) * esat_##P / (TT + 273.2f);

// ---------------------------------------------------------------------------
// Generic one-unit recurrence step (~19 VALU), math unchanged (absmax 0.25).
// ---------------------------------------------------------------------------
#define STEP_G(P, TT, PE, QV, S0, S1, DF_, TMN_, SM_, QM_, G_, QC_, NIS_, NDF_)\
    {                                                                         \
        const float dfdt = fmaf(DF_, (TT), NDF_);                             \
        const float melt = __builtin_amdgcn_fmed3f(dfdt, S0, 0.0f);           \
        const float ps   = ((TT) <= TMN_) ? (P) : 0.0f;                       \
        const float w    = melt - ps;                                         \
        S0 = S0 - w;                                                          \
        const float qs   = fmaxf(S1 - SM_, 0.0f);                             \
        const float m    = fminf(S1, SM_);                                    \
        const float u    = fmaf(G_, S1, QC_);                                 \
        const float qb   = fminf(QM_, __builtin_amdgcn_exp2f(u));             \
        const float npei = (PE)*NIS_;                                         \
        const float A    = (S1 + ((P) + w)) - qs;                             \
        const float B    = fmaf(m, npei, A);                                  \
        S1 = fmaxf(B - qb, 0.0f);                                             \
        QV = qb + qs;                                                         \
    }

// Paired step: two units (A,B) share one LDS value; chains interleave (ILP).
#define STEP2(W, QQ)                                                          \
    STEP_G(W.x, W.y, W.z, QQ.x, s0A, s1A, DFA, TMNA, SMA, QMA, gA, qcA, nisA, ndfA); \
    STEP_G(W.x, W.y, W.z, QQ.y, s0B, s1B, DFB, TMNB, SMB, QMB, gB, qcB, nisB, ndfB)

// 8-step body: 8 named LDS reads up front (one lgkmcnt batch), then 8 paired
// steps. DOSTORE(i) empty for warmup.
#define BODY8(base, DOSTORE)                                                  \
    {                                                                         \
        const float4 w0 = sd[(base) + 0], w1 = sd[(base) + 1];                \
        const float4 w2 = sd[(base) + 2], w3 = sd[(base) + 3];                \
        const float4 w4 = sd[(base) + 4], w5 = sd[(base) + 5];                \
        const float4 w6 = sd[(base) + 6], w7 = sd[(base) + 7];                \
        float2 qq;                                                            \
        STEP2(w0, qq); DOSTORE(0);                                            \
        STEP2(w1, qq); DOSTORE(1);                                            \
        STEP2(w2, qq); DOSTORE(2);                                            \
        STEP2(w3, qq); DOSTORE(3);                                            \
        STEP2(w4, qq); DOSTORE(4);                                            \
        STEP2(w5, qq); DOSTORE(5);                                            \
        STEP2(w6, qq); DOSTORE(6);                                            \
        STEP2(w7, qq); DOSTORE(7);                                            \
    }
#define NOSTORE(i)
#define QSTORE(i) *(float2*)(qbase + off + (unsigned)(i) * 2048u) = qq

// ---------------------------------------------------------------------------
// Pass A: Lindley segment aggregates. One block per 200-step segment; each
// thread owns units 2*tid, 2*tid+1 (shared LDS reads, adjacent dm stores).
// ---------------------------------------------------------------------------
__global__ __launch_bounds__(256, 1)
void lindley_agg_kernel(const float* __restrict__ x,
                        const float* __restrict__ df_,
                        const float* __restrict__ tmax_,
                        const float* __restrict__ tmin_,
                        double2* __restrict__ dm) {
    __shared__ float4 sd[LBASE];
    const int chunk = blockIdx.x;          // 0..249
    const int h0    = 2 * (int)threadIdx.x;
    const int h1    = h0 + 1;

    const float DFA = df_[h0], TMXA = tmax_[h0], TMNA = tmin_[h0];
    const float DFB = df_[h1], TMXB = tmax_[h1], TMNB = tmin_[h1];
    const float ndfA = -(DFA * TMXA);
    const float ndfB = -(DFB * TMXB);

    const int cL = chunk * LBASE;
    for (int i = threadIdx.x; i < LBASE; i += 256) {
        PET_FROM_X(cL + i, p, tt, pe);
        sd[i] = make_float4(p, tt, pe, 0.f);
    }
    __syncthreads();

    double DA = 0.0, MA = -1.0e300, DB = 0.0, MB = -1.0e300;
    for (int it = 0; it < LBASE / 8; ++it) {
        const int base = it * 8;
#pragma unroll
        for (int i = 0; i < 8; ++i) {
            const float4 v = sd[base + i];
            const float capA = fmaxf(fmaf(DFA, v.y, ndfA), 0.0f);
            const float psA  = (v.y <= TMNA) ? v.x : 0.0f;
            const double dA  = (double)psA - (double)capA;
            DA += dA; MA = fmax(MA + dA, (double)psA);
            const float capB = fmaxf(fmaf(DFB, v.y, ndfB), 0.0f);
            const float psB  = (v.y <= TMNB) ? v.x : 0.0f;
            const double dB  = (double)psB - (double)capB;
            DB += dB; MB = fmax(MB + dB, (double)psB);
        }
    }
    dm[chunk * HID + h0] = make_double2(DA, MA);
    dm[chunk * HID + h1] = make_double2(DB, MB);
}

// ---------------------------------------------------------------------------
// Pass B: compose the 250 segment maps sequentially per unit -> EXACT s0 at
// every boundary. Depth-4 rotating prefetch; 249 composes = 61*4 + 5, last
// reload reads dm[249] -> no over-read.
// ---------------------------------------------------------------------------
__global__ __launch_bounds__(64)
void lindley_scan_kernel(const double2* __restrict__ dm,
                         float* __restrict__ s0b) {
    const int h = blockIdx.x * 64 + threadIdx.x;   // grid = 8 blocks
    const double2* dp = dm + h;
    double xv = 0.0;
    s0b[h] = 0.0f;                                  // boundary 0: s0 = 0

#define COMP(a, c)                                                            \
    {                                                                         \
        PIN2D(a);                                                             \
        xv = fmax(xv + a.x, a.y);                                             \
        s0b[(size_t)((c) + 1) * HID + h] = (float)xv;                         \
    }
#define COMPS(PJ, c)                                                          \
    { COMP(PJ, c); PJ = dp[(size_t)((c) + 4) * HID]; }

    double2 p0 = dp[0];
    double2 p1 = dp[(size_t)1 * HID];
    double2 p2 = dp[(size_t)2 * HID];
    double2 p3 = dp[(size_t)3 * HID];

    for (int j = 0; j < 61; ++j) {                  // composes 0..243
        const int c = 4 * j;
        COMPS(p0, c);
        COMPS(p1, c + 1);
        COMPS(p2, c + 2);
        COMPS(p3, c + 3);                           // j=60 reloads dm[247]: ok
    }
    COMPS(p0, 244);                                 // reloads dm[248]
    COMPS(p1, 245);                                 // reloads dm[249]
    COMP(p2, 246);
    COMP(p3, 247);
    COMP(p0, 248);                                  // boundary 249 written
#undef COMPS
#undef COMP
}

// ---------------------------------------------------------------------------
// Main chunked scan, LDS-staged, PAIRED (2 units/thread). r15/r17/r18
// normalize to constant per-SIMD throughput (~115-130 cy/step) = ISSUE-bound;
// pairing shares the ds_read, the store (dwordx2), addressing and loop
// overhead between 2 units and interleaves 2 independent chains (ILP).
// One block per chunk (256 thr x 2 units = 512), 250 blocks = 1/CU (k=1).
// L=200, W=400 (validated warm length, boundary-aligned: s0b[chunk-2] is the
// exact s0 at t = cL-400). Chunks 0-1 start at t=0 (fully exact).
// ---------------------------------------------------------------------------
__global__ __launch_bounds__(256, 1)
void hydro_chunk_kernel(const float* __restrict__ x,
                        const float* __restrict__ s0b,
                        const float* __restrict__ f_,
                        const float* __restrict__ smax_,
                        const float* __restrict__ qmax_,
                        const float* __restrict__ df_,
                        const float* __restrict__ tmax_,
                        const float* __restrict__ tmin_,
                        float*       __restrict__ q) {
    __shared__ float4 sd[SDMAX];
    const int chunk = blockIdx.x;          // 0..249
    const int h0    = 2 * (int)threadIdx.x;
    const int h1    = h0 + 1;

    const float FA = f_[h0], SMA = smax_[h0], QMA = qmax_[h0];
    const float DFA = df_[h0], TMXA = tmax_[h0], TMNA = tmin_[h0];
    const float FB = f_[h1], SMB = smax_[h1], QMB = qmax_[h1];
    const float DFB = df_[h1], TMXB = tmax_[h1], TMNB = tmin_[h1];

    const float gA   = FA * 1.4426950408889634f;
    const float qcA  = __log2f(QMA) - gA * SMA;
    const float nisA = -1.0f / SMA;
    const float ndfA = -(DFA * TMXA);
    const float gB   = FB * 1.4426950408889634f;
    const float qcB  = __log2f(QMB) - gB * SMB;
    const float nisB = -1.0f / SMB;
    const float ndfB = -(DFB * TMXB);

    const int cL    = chunk * LBASE;
    const int start = (chunk >= WARMCH) ? (cL - WARM) : 0;  // boundary-aligned
    const int n     = (cL - start) + LBASE;                 // 200/400/600

    for (int i = threadIdx.x; i < n; i += 256) {
        PET_FROM_X(start + i, p, tt, pe);
        sd[i] = make_float4(p, tt, pe, 0.f);
    }
    __syncthreads();

    float s0A = (chunk >= WARMCH) ? s0b[(chunk - WARMCH) * HID + h0] : 0.0f;
    float s0B = (chunk >= WARMCH) ? s0b[(chunk - WARMCH) * HID + h1] : 0.0f;
    float s1A = 0.0f, s1B = 0.0f;

    const int nWarm8 = (cL - start) >> 3;             // 0, 25, or 50
    for (int it = 0; it < nWarm8; ++it) {
        BODY8(it * 8, NOSTORE);
    }

    char* qbase  = (char*)q;
    unsigned off = (unsigned)cL * 2048u + (unsigned)h0 * 4u;
    const int wbase = cL - start;                     // 0, 200, or 400

    for (int it = 0; it < LBASE / 8; ++it) {          // 25 output bodies
        BODY8(wbase + it * 8, QSTORE);
        off += 8u * 2048u;
    }
}

// ---------------------------------------------------------------------------
// Fallback: full-serial scan (correct for any ws_size), pet inline.
// ---------------------------------------------------------------------------
__global__ __launch_bounds__(64)
void hydro_serial_kernel(const float* __restrict__ x,
                         const float* __restrict__ f_,
                         const float* __restrict__ smax_,
                         const float* __restrict__ qmax_,
                         const float* __restrict__ df_,
                         const float* __restrict__ tmax_,
                         const float* __restrict__ tmin_,
                         float* __restrict__ q) {
    const int h = blockIdx.x * 64 + threadIdx.x;
    const float F = f_[h], SM = smax_[h], QM = qmax_[h];
    const float DF = df_[h], TMX = tmax_[h], TMN = tmin_[h];
    const float g   = F * 1.4426950408889634f;
    const float qc  = __log2f(QM) - g * SM;
    const float nis = -1.0f / SM;
    const float ndf = -(DF * TMX);
    float s0 = 0.f, s1 = 0.f;
    for (int t = 0; t < T_STEPS; ++t) {
        PET_FROM_X(t, p, tt, pe);
        float qv;
        STEP_G(p, tt, pe, qv, s0, s1, DF, TMN, SM, QM, g, qc, nis, ndf);
        q[(size_t)t * HID + h] = qv;
    }
}

// ---------------------------------------------------------------------------
extern "C" void kernel_launch(void* const* d_in, const int* in_sizes, int n_in,
                              void* d_out, int out_size, void* d_ws,
                              size_t ws_size, hipStream_t stream) {
    const float* x    = (const float*)d_in[0];
    const float* f    = (const float*)d_in[1];
    const float* smax = (const float*)d_in[2];
    const float* qmax = (const float*)d_in[3];
    const float* df   = (const float*)d_in[4];
    const float* tmax = (const float*)d_in[5];
    const float* tmin = (const float*)d_in[6];
    float* q = (float*)d_out;

    const size_t DM_BYTES  = (size_t)CHUNKS * HID * sizeof(double2); // ~2.0 MB
    const size_t S0B_OFF   = DM_BYTES;
    const size_t S0B_BYTES = (size_t)CHUNKS * HID * sizeof(float);   // ~512 KB
    const size_t NEED      = S0B_OFF + S0B_BYTES;

    if (ws_size >= NEED) {
        double2* dm  = (double2*)d_ws;
        float*   s0b = (float*)((char*)d_ws + S0B_OFF);

        lindley_agg_kernel<<<CHUNKS, 256, 0, stream>>>(x, df, tmax, tmin, dm);
        lindley_scan_kernel<<<HID / 64, 64, 0, stream>>>(dm, s0b);
        hydro_chunk_kernel<<<CHUNKS, 256, 0, stream>>>(
            x, s0b, f, smax, qmax, df, tmax, tmin, q);
    } else {
        hydro_serial_kernel<<<HID / 64, 64, 0, stream>>>(
            x, f, smax, qmax, df, tmax, tmin, q);
    }
}

// Round 24
// 70.152 us; speedup vs baseline: 1.2722x; 1.2722x over previous
//
#include <hip/hip_runtime.h>

#define T_STEPS 50000
#define HID     512
#define LBASE   400
#define CHUNKS  125            // 50000 = 125*400 exactly -> NO tail chunk
#define WARM    LBASE          // 400-step warmup (validated r6/r19: absmax 0.25)
#define SDMAX   (WARM + LBASE) // 800 float4 = 12800 B LDS
#define OUTB    (LBASE / 8)    // 50 output bodies of 8 steps

static_assert(T_STEPS == CHUNKS * LBASE, "exact chunking");
static_assert(LBASE % 16 == 0, "even body count");
static_assert(CHUNKS - 1 == 30 * 4 + 4, "scan rotation layout");

#define PIN2D(a) asm volatile("" : "+v"(a.x), "+v"(a.y))

// Memory-ordering fence for optimizer + MIR scheduler: ds_reads issued above
// cannot sink below (toward their uses). No asm memory ops -> no crash
// surface (r22/r23 asm path abandoned per decision rule).
#define FENCE asm volatile("" ::: "memory")

// C-level load of one 8-step body into named registers (SSA; no copies).
#define CLOAD8(Bf, ib)                                                        \
    {                                                                         \
        const int b_ = (ib) * 8;                                              \
        Bf##0 = sd[b_ + 0]; Bf##1 = sd[b_ + 1];                               \
        Bf##2 = sd[b_ + 2]; Bf##3 = sd[b_ + 3];                               \
        Bf##4 = sd[b_ + 4]; Bf##5 = sd[b_ + 5];                               \
        Bf##6 = sd[b_ + 6]; Bf##7 = sd[b_ + 7];                               \
    }

// pet from raw x row (x is 600 KB -> L2-resident after first touch)
#define PET_FROM_X(t, P, TT, PE)                                              \
    const float P  = x[3 * (t) + 0];                                          \
    const float TT = x[3 * (t) + 1];                                          \
    const float ld_##P = x[3 * (t) + 2];                                      \
    const float esat_##P = 0.611f * __expf(17.3f * TT / (TT + 237.3f));       \
    const float PE = 29.8f * (ld_##P * 24.0f) * esat_##P / (TT + 273.2f);

// ---------------------------------------------------------------------------
// One recurrence step (~19 VALU), math unchanged (validated absmax 0.25).
// ---------------------------------------------------------------------------
#define STEP(P, TT, PE, QV)                                                   \
    {                                                                         \
        const float dfdt = fmaf(DF, (TT), ndftmx);                            \
        const float melt = __builtin_amdgcn_fmed3f(dfdt, s0, 0.0f);           \
        const float ps   = ((TT) <= TMN) ? (P) : 0.0f;                        \
        const float w    = melt - ps;                                         \
        s0 = s0 - w;                                                          \
        const float qs   = fmaxf(s1 - SM, 0.0f);                              \
        const float m    = fminf(s1, SM);                                     \
        const float u    = fmaf(g, s1, qc);                                   \
        const float qb   = fminf(QM, __builtin_amdgcn_exp2f(u));              \
        const float npei = (PE)*ninv_sm;                                      \
        const float A    = (s1 + ((P) + w)) - qs;                             \
        const float B    = fmaf(m, npei, A);                                  \
        s1 = fmaxf(B - qb, 0.0f);                                             \
        QV = qb + qs;                                                         \
    }

#define NOSTORE(i)
#define QSTORE(i) *(float*)(qbase + off + (unsigned)(i) * 2048u) = qv

// Paste target isolated — (Bf##0).x, NOT Bf##0.x (r21 lesson).
#define COMP8(Bf, DOSTORE)                                                    \
    {                                                                         \
        float qv;                                                             \
        STEP((Bf##0).x, (Bf##0).y, (Bf##0).z, qv); DOSTORE(0);                \
        STEP((Bf##1).x, (Bf##1).y, (Bf##1).z, qv); DOSTORE(1);                \
        STEP((Bf##2).x, (Bf##2).y, (Bf##2).z, qv); DOSTORE(2);                \
        STEP((Bf##3).x, (Bf##3).y, (Bf##3).z, qv); DOSTORE(3);                \
        STEP((Bf##4).x, (Bf##4).y, (Bf##4).z, qv); DOSTORE(4);                \
        STEP((Bf##5).x, (Bf##5).y, (Bf##5).z, qv); DOSTORE(5);                \
        STEP((Bf##6).x, (Bf##6).y, (Bf##6).z, qv); DOSTORE(6);                \
        STEP((Bf##7).x, (Bf##7).y, (Bf##7).z, qv); DOSTORE(7);                \
    }

// ---------------------------------------------------------------------------
// Pass A: Lindley segment aggregates (r19 structure, 1 unit/thread).
// Snow bucket is max-plus linear: s0' = max(s0 + d, ps); segment (D, M)
// composes as x -> max(x + D, M).
// ---------------------------------------------------------------------------
__global__ __launch_bounds__(256, 1)
void lindley_agg_kernel(const float* __restrict__ x,
                        const float* __restrict__ df_,
                        const float* __restrict__ tmax_,
                        const float* __restrict__ tmin_,
                        double2* __restrict__ dm) {
    __shared__ float4 sd[LBASE];
    const int b     = blockIdx.x;          // 0..CHUNKS*2-1
    const int chunk = b >> 1;
    const int h     = ((b & 1) << 8) | (int)threadIdx.x;

    const float DF = df_[h], TMX = tmax_[h], TMN = tmin_[h];
    const float ndftmx = -(DF * TMX);

    const int cL = chunk * LBASE;
    for (int i = threadIdx.x; i < LBASE; i += 256) {
        PET_FROM_X(cL + i, p, tt, pe);
        sd[i] = make_float4(p, tt, pe, 0.f);
    }
    __syncthreads();

    double D = 0.0, M = -1.0e300;
    for (int it = 0; it < LBASE / 16; ++it) {
        const int base = it * 16;
#pragma unroll
        for (int i = 0; i < 16; ++i) {
            const float4 v = sd[base + i];
            const float cap = fmaxf(fmaf(DF, v.y, ndftmx), 0.0f);
            const float ps  = (v.y <= TMN) ? v.x : 0.0f;
            const double d  = (double)ps - (double)cap;
            D += d;
            M = fmax(M + d, (double)ps);
        }
    }
    dm[chunk * HID + h] = make_double2(D, M);
}

// ---------------------------------------------------------------------------
// Pass B: compose the 125 chunk maps sequentially per unit -> EXACT s0 at
// every boundary (r19 structure). 124 composes = 30*4 + 4; no over-read.
// ---------------------------------------------------------------------------
__global__ __launch_bounds__(64)
void lindley_scan_kernel(const double2* __restrict__ dm,
                         float* __restrict__ s0b) {
    const int h = blockIdx.x * 64 + threadIdx.x;   // grid = 8 blocks
    const double2* dp = dm + h;
    double xv = 0.0;
    s0b[h] = 0.0f;                                  // boundary 0: s0 = 0

#define COMP(a, c)                                                            \
    {                                                                         \
        PIN2D(a);                                                             \
        xv = fmax(xv + a.x, a.y);                                             \
        s0b[(size_t)((c) + 1) * HID + h] = (float)xv;                         \
    }
#define COMPS(PJ, c)                                                          \
    { COMP(PJ, c); PJ = dp[(size_t)((c) + 4) * HID]; }

    double2 p0 = dp[0];
    double2 p1 = dp[(size_t)1 * HID];
    double2 p2 = dp[(size_t)2 * HID];
    double2 p3 = dp[(size_t)3 * HID];

    for (int j = 0; j < 30; ++j) {                  // composes 0..119
        const int c = 4 * j;
        COMPS(p0, c);
        COMPS(p1, c + 1);
        COMPS(p2, c + 2);
        COMPS(p3, c + 3);                           // j=29 reloads dm[123]: ok
    }
    COMP(p0, 120);
    COMP(p1, 121);
    COMP(p2, 122);
    COMP(p3, 123);                                  // boundary 124 written
#undef COMPS
#undef COMP
}

// ---------------------------------------------------------------------------
// Main chunked scan: r19 geometry (L=W=400, 250 blocks = 1/CU, 1 unit/thread,
// 800 steps/wave), C-level software pipeline with memory fences: each 8-step
// body's loads are issued one body EARLY and pinned above the intervening
// COMP8 by asm("":::"memory") — loads stay in flight under ~300cy of VALU.
// ALIGNMENT INVARIANT: warm span = LBASE exactly, so s0b[chunk-1] (exact s0
// at t = cL-LBASE) applies at start. Chunk 0 starts at t=0 (fully exact).
// ---------------------------------------------------------------------------
__global__ __launch_bounds__(256, 1)
void hydro_chunk_kernel(const float* __restrict__ x,
                        const float* __restrict__ s0b,
                        const float* __restrict__ f_,
                        const float* __restrict__ smax_,
                        const float* __restrict__ qmax_,
                        const float* __restrict__ df_,
                        const float* __restrict__ tmax_,
                        const float* __restrict__ tmin_,
                        float*       __restrict__ q) {
    __shared__ float4 sd[SDMAX];
    const int b     = blockIdx.x;          // 0..CHUNKS*2-1
    const int chunk = b >> 1;
    const int h     = ((b & 1) << 8) | (int)threadIdx.x;

    const float F   = f_[h];
    const float SM  = smax_[h];
    const float QM  = qmax_[h];
    const float DF  = df_[h];
    const float TMX = tmax_[h];
    const float TMN = tmin_[h];

    const float g       = F * 1.4426950408889634f;   // f * log2(e)
    const float qc      = __log2f(QM) - g * SM;       // log2(qmax) - g*smax
    const float ninv_sm = -1.0f / SM;
    const float ndftmx  = -(DF * TMX);

    const int cL    = chunk * LBASE;
    const int start = (chunk >= 1) ? (cL - WARM) : 0;   // boundary-aligned
    const int n     = (chunk >= 1) ? (WARM + LBASE) : LBASE;

    for (int i = threadIdx.x; i < n; i += 256) {
        PET_FROM_X(start + i, p, tt, pe);
        sd[i] = make_float4(p, tt, pe, 0.f);
    }
    __syncthreads();

    float s0 = (chunk >= 1) ? s0b[(chunk - 1) * HID + h] : 0.0f;
    float s1 = 0.0f;

    float4 A0, A1, A2, A3, A4, A5, A6, A7;
    float4 B0, B1, B2, B3, B4, B5, B6, B7;

    const int wp = (chunk >= 1) ? (WARM / 16) : 0;    // warm PAIRS (25 or 0)
    const int wB = 2 * wp;                            // warm bodies (50 or 0)

    CLOAD8(A, 0);
    CLOAD8(B, 1);
    FENCE;

    // Warm phase: bodies 0..wB-1, no stores. Each COMP consumes a body
    // loaded >= 1 body ago; reloads pinned above the next COMP by FENCE.
    for (int j = 0; j < wp; ++j) {
        COMP8(A, NOSTORE); CLOAD8(A, 2 * j + 2); FENCE;
        COMP8(B, NOSTORE); CLOAD8(B, 2 * j + 3); FENCE;
    }

    char* qbase  = (char*)q;
    unsigned off = (unsigned)cL * 2048u + (unsigned)h * 4u;

    // Output phase: bodies wB..wB+49. 24 pipelined pairs + peeled last pair.
    for (int j = 0; j < OUTB / 2 - 1; ++j) {
        COMP8(A, QSTORE); off += 16384u; CLOAD8(A, wB + 2 * j + 2); FENCE;
        COMP8(B, QSTORE); off += 16384u; CLOAD8(B, wB + 2 * j + 3); FENCE;
    }
    COMP8(A, QSTORE); off += 16384u;                  // body wB+48
    COMP8(B, QSTORE);                                 // body wB+49
}

// ---------------------------------------------------------------------------
// Fallback: full-serial scan (correct for any ws_size), pet inline.
// ---------------------------------------------------------------------------
__global__ __launch_bounds__(64)
void hydro_serial_kernel(const float* __restrict__ x,
                         const float* __restrict__ f_,
                         const float* __restrict__ smax_,
                         const float* __restrict__ qmax_,
                         const float* __restrict__ df_,
                         const float* __restrict__ tmax_,
                         const float* __restrict__ tmin_,
                         float* __restrict__ q) {
    const int h = blockIdx.x * 64 + threadIdx.x;
    const float F = f_[h], SM = smax_[h], QM = qmax_[h];
    const float DF = df_[h], TMX = tmax_[h], TMN = tmin_[h];
    const float g       = F * 1.4426950408889634f;
    const float qc      = __log2f(QM) - g * SM;
    const float ninv_sm = -1.0f / SM;
    const float ndftmx  = -(DF * TMX);
    float s0 = 0.f, s1 = 0.f;
    for (int t = 0; t < T_STEPS; ++t) {
        PET_FROM_X(t, p, tt, pe);
        float qv;
        STEP(p, tt, pe, qv);
        q[(size_t)t * HID + h] = qv;
    }
}

// ---------------------------------------------------------------------------
extern "C" void kernel_launch(void* const* d_in, const int* in_sizes, int n_in,
                              void* d_out, int out_size, void* d_ws,
                              size_t ws_size, hipStream_t stream) {
    const float* x    = (const float*)d_in[0];
    const float* f    = (const float*)d_in[1];
    const float* smax = (const float*)d_in[2];
    const float* qmax = (const float*)d_in[3];
    const float* df   = (const float*)d_in[4];
    const float* tmax = (const float*)d_in[5];
    const float* tmin = (const float*)d_in[6];
    float* q = (float*)d_out;

    const size_t DM_BYTES  = (size_t)CHUNKS * HID * sizeof(double2); // ~1.0 MB
    const size_t S0B_OFF   = DM_BYTES;
    const size_t S0B_BYTES = (size_t)CHUNKS * HID * sizeof(float);   // ~256 KB
    const size_t NEED      = S0B_OFF + S0B_BYTES;

    if (ws_size >= NEED) {
        double2* dm  = (double2*)d_ws;
        float*   s0b = (float*)((char*)d_ws + S0B_OFF);

        lindley_agg_kernel<<<CHUNKS * 2, 256, 0, stream>>>(x, df, tmax, tmin, dm);
        lindley_scan_kernel<<<HID / 64, 64, 0, stream>>>(dm, s0b);
        hydro_chunk_kernel<<<CHUNKS * 2, 256, 0, stream>>>(
            x, s0b, f, smax, qmax, df, tmax, tmin, q);
    } else {
        hydro_serial_kernel<<<HID / 64, 64, 0, stream>>>(
            x, f, smax, qmax, df, tmax, tmin, q);
    }
}